// Round 1
// baseline (187.724 us; speedup 1.0000x reference)
//
#include <hip/hip_runtime.h>

// E-MHSA (PVT-style spatial-reduction attention), MI355X/gfx950.
// B=4, N=3136, C=384, H=12, d=32, SR=2 -> Nk=784.
// Pipeline: cast -> pool+BN -> GEMM q/k/v (bf16 MFMA) -> flash attn -> GEMM out.

typedef __bf16 bf16x8 __attribute__((ext_vector_type(8)));
typedef unsigned short u16x8 __attribute__((ext_vector_type(8)));
typedef float f32x4 __attribute__((ext_vector_type(4)));

#define SCALE 0.17677669529663689f   // 32^-0.5
#define NTOK 3136
#define NKV 784
#define CCH 384

__device__ __forceinline__ unsigned short f2b(float f) {
  union { float f; unsigned u; } v; v.f = f;
  unsigned r = v.u + 0x7fffu + ((v.u >> 16) & 1u);   // RNE
  return (unsigned short)(r >> 16);
}

__device__ __forceinline__ bf16x8 ldsb8(const unsigned short* p) {
  u16x8 v = *(const u16x8*)p;
  return __builtin_bit_cast(bf16x8, v);
}

// async global->LDS, 16B per lane; lds dest = wave-uniform base + lane*16
__device__ __forceinline__ void gload16(const void* g, void* lds) {
  auto* g1 = reinterpret_cast<const __attribute__((address_space(1))) unsigned int*>(
      reinterpret_cast<uintptr_t>(g));
  auto* l3 = reinterpret_cast<__attribute__((address_space(3))) unsigned int*>(
      reinterpret_cast<uintptr_t>(lds));
  __builtin_amdgcn_global_load_lds(g1, l3, 16, 0, 0);
}

// ---------------- elementwise prep ----------------

__global__ __launch_bounds__(256) void castw_kernel(
    const float* __restrict__ a, const float* __restrict__ b,
    const float* __restrict__ c, const float* __restrict__ d,
    unsigned short* __restrict__ oa, unsigned short* __restrict__ ob,
    unsigned short* __restrict__ oc, unsigned short* __restrict__ od) {
  int i = blockIdx.x * 256 + threadIdx.x;  // < 36864 (=147456/4)
  float4 va = ((const float4*)a)[i];
  float4 vb = ((const float4*)b)[i];
  float4 vc = ((const float4*)c)[i];
  float4 vd = ((const float4*)d)[i];
  ushort4 ra; ra.x = f2b(va.x); ra.y = f2b(va.y); ra.z = f2b(va.z); ra.w = f2b(va.w);
  ushort4 rb; rb.x = f2b(vb.x); rb.y = f2b(vb.y); rb.z = f2b(vb.z); rb.w = f2b(vb.w);
  ushort4 rc; rc.x = f2b(vc.x); rc.y = f2b(vc.y); rc.z = f2b(vc.z); rc.w = f2b(vc.w);
  ushort4 rd; rd.x = f2b(vd.x); rd.y = f2b(vd.y); rd.z = f2b(vd.z); rd.w = f2b(vd.w);
  ((ushort4*)oa)[i] = ra; ((ushort4*)ob)[i] = rb;
  ((ushort4*)oc)[i] = rc; ((ushort4*)od)[i] = rd;
}

__global__ __launch_bounds__(256) void castx_kernel(
    const float* __restrict__ x, unsigned short* __restrict__ o) {
  int i = blockIdx.x * 256 + threadIdx.x;  // < 1204224 (=4*3136*384/4)
  float4 v = ((const float4*)x)[i];
  ushort4 r; r.x = f2b(v.x); r.y = f2b(v.y); r.z = f2b(v.z); r.w = f2b(v.w);
  ((ushort4*)o)[i] = r;
}

// avgpool(4 tokens) + BatchNorm (running stats), fp32 math -> bf16
__global__ __launch_bounds__(256) void poolbn_kernel(
    const float* __restrict__ x, const float* __restrict__ gam,
    const float* __restrict__ bet, const float* __restrict__ mea,
    const float* __restrict__ var, unsigned short* __restrict__ xo) {
  int i = blockIdx.x * 256 + threadIdx.x;  // < 301056 (=4*784*96)
  int c4 = i % 96;
  int row = i / 96;           // b*784 + nk
  int b = row / NKV, nk = row - b * NKV;
  const float4* x4 = (const float4*)x;
  size_t base = ((size_t)(b * NTOK + nk * 4)) * 96 + c4;
  float sx = 0.f, sy = 0.f, sz = 0.f, sw = 0.f;
#pragma unroll
  for (int r = 0; r < 4; ++r) {
    float4 v = x4[base + (size_t)r * 96];
    sx += v.x; sy += v.y; sz += v.z; sw += v.w;
  }
  int c = c4 * 4;
  float g0 = gam[c], g1 = gam[c + 1], g2 = gam[c + 2], g3 = gam[c + 3];
  float b0 = bet[c], b1 = bet[c + 1], b2 = bet[c + 2], b3 = bet[c + 3];
  float m0 = mea[c], m1 = mea[c + 1], m2 = mea[c + 2], m3 = mea[c + 3];
  float i0 = rsqrtf(var[c] + 1e-5f), i1 = rsqrtf(var[c + 1] + 1e-5f);
  float i2 = rsqrtf(var[c + 2] + 1e-5f), i3 = rsqrtf(var[c + 3] + 1e-5f);
  ushort4 r;
  r.x = f2b((sx * 0.25f - m0) * i0 * g0 + b0);
  r.y = f2b((sy * 0.25f - m1) * i1 * g1 + b1);
  r.z = f2b((sz * 0.25f - m2) * i2 * g2 + b2);
  r.w = f2b((sw * 0.25f - m3) * i3 * g3 + b3);
  ((ushort4*)xo)[i] = r;
}

// ---------------- GEMM: C[m][n] = sum_k A[m][k]*W[n][k] + bias[n] ----------------
// A bf16 [M][384], W bf16 [384][384] (row n = output col), K=N=384.
// 128x128 tile, BK=32, 4 waves (2x2), each wave 64x64 = 4x4 fragments.
// EPI: 0 = bf16 row-major out, 1 = bf16 scatter to vt[b][h][d][j], 2 = fp32 out.
template <int EPI>
__global__ __launch_bounds__(256) void gemm_bt(
    const unsigned short* __restrict__ A, const unsigned short* __restrict__ Bt,
    const float* __restrict__ bias, void* __restrict__ out, int M) {
  __shared__ unsigned short sA[128 * 32];
  __shared__ unsigned short sB[128 * 32];
  const int t = threadIdx.x, w = t >> 6, l = t & 63;
  const int row0 = blockIdx.x * 128, col0 = blockIdx.y * 128;
  const int wr = w >> 1, wc = w & 1;

  f32x4 acc[4][4];
#pragma unroll
  for (int m = 0; m < 4; ++m)
#pragma unroll
    for (int n = 0; n < 4; ++n) acc[m][n] = (f32x4){0.f, 0.f, 0.f, 0.f};

  for (int kk = 0; kk < 12; ++kk) {
    if (kk) __syncthreads();
#pragma unroll
    for (int i = 0; i < 2; ++i) {
      int r = row0 + i * 64 + w * 16 + (l >> 2);
      if (r > M - 1) r = M - 1;
      gload16(A + (size_t)r * CCH + kk * 32 + (l & 3) * 8,
              (char*)sA + i * 4096 + w * 1024);
      int rb = col0 + i * 64 + w * 16 + (l >> 2);
      gload16(Bt + (size_t)rb * CCH + kk * 32 + (l & 3) * 8,
              (char*)sB + i * 4096 + w * 1024);
    }
    __syncthreads();
    bf16x8 af[4], bf[4];
#pragma unroll
    for (int m = 0; m < 4; ++m)
      af[m] = ldsb8(&sA[(wr * 64 + m * 16 + (l & 15)) * 32 + (l >> 4) * 8]);
#pragma unroll
    for (int n = 0; n < 4; ++n)
      bf[n] = ldsb8(&sB[(wc * 64 + n * 16 + (l & 15)) * 32 + (l >> 4) * 8]);
#pragma unroll
    for (int m = 0; m < 4; ++m)
#pragma unroll
      for (int n = 0; n < 4; ++n)
        acc[m][n] = __builtin_amdgcn_mfma_f32_16x16x32_bf16(af[m], bf[n], acc[m][n], 0, 0, 0);
  }

#pragma unroll
  for (int m = 0; m < 4; ++m) {
#pragma unroll
    for (int r = 0; r < 4; ++r) {
      int row = row0 + wr * 64 + m * 16 + (l >> 4) * 4 + r;
      if (row >= M) continue;
#pragma unroll
      for (int n = 0; n < 4; ++n) {
        int col = col0 + wc * 64 + n * 16 + (l & 15);
        float v = acc[m][n][r] + bias[col];
        if constexpr (EPI == 0) {
          ((unsigned short*)out)[(size_t)row * CCH + col] = f2b(v);
        } else if constexpr (EPI == 2) {
          ((float*)out)[(size_t)row * CCH + col] = v;
        } else {
          int b_ = row / NKV, j = row - b_ * NKV;
          int h_ = col >> 5, d = col & 31;
          ((unsigned short*)out)[((size_t)((b_ * 12 + h_) * 32 + d)) * NKV + j] = f2b(v);
        }
      }
    }
  }
}

// ---------------- flash attention ----------------
// grid: b*H*(N/64).  WG: 4 waves, wave w owns q rows [q0+16w, q0+16w+16).
// KV tiles of 64 (13 tiles; cols >=784 masked).
__global__ __launch_bounds__(256) void attn_kernel(
    const unsigned short* __restrict__ qb, const unsigned short* __restrict__ kb,
    const unsigned short* __restrict__ vtb, unsigned short* __restrict__ ob) {
  __shared__ unsigned short sQ[64 * 32];
  __shared__ unsigned short sK[64 * 32];
  __shared__ unsigned short sV[32 * 64];   // V^T tile: [d][j]
  __shared__ unsigned short sP[4][16 * 64];

  const int bx = blockIdx.x;
  const int qt = bx % 49;
  const int h = (bx / 49) % 12;
  const int b = bx / 588;
  const int t = threadIdx.x, w = t >> 6, l = t & 63;
  const int q0 = qt * 64;

  {  // stage Q tile [64][32]
    int row = q0 + w * 16 + (l >> 2);
    gload16(qb + ((size_t)(b * NTOK + row)) * CCH + h * 32 + (l & 3) * 8,
            (char*)sQ + w * 1024);
  }
  __syncthreads();
  bf16x8 aq = ldsb8(&sQ[(w * 16 + (l & 15)) * 32 + (l >> 4) * 8]);

  float mr[4], lr[4];
  f32x4 acc0 = (f32x4){0.f, 0.f, 0.f, 0.f};
  f32x4 acc1 = (f32x4){0.f, 0.f, 0.f, 0.f};
#pragma unroll
  for (int r = 0; r < 4; ++r) { mr[r] = -1e30f; lr[r] = 0.f; }

  for (int tt = 0; tt < 13; ++tt) {
    const int j0 = tt * 64;
    if (tt) __syncthreads();
    {  // stage K tile [64][32]
      int j = j0 + w * 16 + (l >> 2);
      if (j > NKV - 1) j = NKV - 1;
      gload16(kb + ((size_t)(b * NKV + j)) * CCH + h * 32 + (l & 3) * 8,
              (char*)sK + w * 1024);
    }
    {  // stage V^T tile [32][64]
      int jc = j0 + (l & 7) * 8;
      if (jc > NKV - 8) jc = 0;   // pad cols -> any finite data (P=0 there)
      int d = w * 8 + (l >> 3);
      gload16(vtb + ((size_t)((b * 12 + h) * 32 + d)) * NKV + jc,
              (char*)sV + w * 1024);
    }
    __syncthreads();

    f32x4 s[4];
#pragma unroll
    for (int n = 0; n < 4; ++n) {
      bf16x8 kf = ldsb8(&sK[(n * 16 + (l & 15)) * 32 + (l >> 4) * 8]);
      s[n] = __builtin_amdgcn_mfma_f32_16x16x32_bf16(aq, kf, (f32x4){0.f, 0.f, 0.f, 0.f}, 0, 0, 0);
    }

    const bool tail = (j0 + 64 > NKV);
    float p[4][4], tmax[4];
#pragma unroll
    for (int r = 0; r < 4; ++r) tmax[r] = -1e30f;
#pragma unroll
    for (int n = 0; n < 4; ++n) {
#pragma unroll
      for (int r = 0; r < 4; ++r) {
        float sv = s[n][r] * SCALE;
        if (tail && (j0 + n * 16 + (l & 15)) >= NKV) sv = -1e30f;
        p[n][r] = sv;
        tmax[r] = fmaxf(tmax[r], sv);
      }
    }
#pragma unroll
    for (int r = 0; r < 4; ++r) {
      tmax[r] = fmaxf(tmax[r], __shfl_xor(tmax[r], 1, 16));
      tmax[r] = fmaxf(tmax[r], __shfl_xor(tmax[r], 2, 16));
      tmax[r] = fmaxf(tmax[r], __shfl_xor(tmax[r], 4, 16));
      tmax[r] = fmaxf(tmax[r], __shfl_xor(tmax[r], 8, 16));
    }
    float alpha[4], psum[4];
#pragma unroll
    for (int r = 0; r < 4; ++r) {
      float mn = fmaxf(mr[r], tmax[r]);
      alpha[r] = __expf(mr[r] - mn);
      mr[r] = mn;
      psum[r] = 0.f;
    }
#pragma unroll
    for (int n = 0; n < 4; ++n)
#pragma unroll
      for (int r = 0; r < 4; ++r) {
        float e = __expf(p[n][r] - mr[r]);
        p[n][r] = e;
        psum[r] += e;
      }
#pragma unroll
    for (int r = 0; r < 4; ++r) {
      psum[r] += __shfl_xor(psum[r], 1, 16);
      psum[r] += __shfl_xor(psum[r], 2, 16);
      psum[r] += __shfl_xor(psum[r], 4, 16);
      psum[r] += __shfl_xor(psum[r], 8, 16);
      lr[r] = lr[r] * alpha[r] + psum[r];
      acc0[r] *= alpha[r];
      acc1[r] *= alpha[r];
    }
    // P -> per-wave LDS in A-fragment layout
#pragma unroll
    for (int n = 0; n < 4; ++n)
#pragma unroll
      for (int r = 0; r < 4; ++r)
        sP[w][((l >> 4) * 4 + r) * 64 + n * 16 + (l & 15)] = f2b(p[n][r]);
    // PV
#pragma unroll
    for (int kkk = 0; kkk < 2; ++kkk) {
      bf16x8 ap = ldsb8(&sP[w][(l & 15) * 64 + kkk * 32 + (l >> 4) * 8]);
      bf16x8 v0 = ldsb8(&sV[(l & 15) * 64 + kkk * 32 + (l >> 4) * 8]);
      bf16x8 v1 = ldsb8(&sV[(16 + (l & 15)) * 64 + kkk * 32 + (l >> 4) * 8]);
      acc0 = __builtin_amdgcn_mfma_f32_16x16x32_bf16(ap, v0, acc0, 0, 0, 0);
      acc1 = __builtin_amdgcn_mfma_f32_16x16x32_bf16(ap, v1, acc1, 0, 0, 0);
    }
  }

#pragma unroll
  for (int r = 0; r < 4; ++r) {
    int row = q0 + w * 16 + (l >> 4) * 4 + r;
    float inv = 1.f / lr[r];
    size_t base = ((size_t)(b * NTOK + row)) * CCH + h * 32;
    ob[base + (l & 15)] = f2b(acc0[r] * inv);
    ob[base + 16 + (l & 15)] = f2b(acc1[r] * inv);
  }
}

// ---------------- launch ----------------

extern "C" void kernel_launch(void* const* d_in, const int* in_sizes, int n_in,
                              void* d_out, int out_size, void* d_ws, size_t ws_size,
                              hipStream_t stream) {
  const float* x   = (const float*)d_in[0];
  const float* Wq  = (const float*)d_in[1];
  const float* bq  = (const float*)d_in[2];
  const float* Wk  = (const float*)d_in[3];
  const float* bk  = (const float*)d_in[4];
  const float* Wv  = (const float*)d_in[5];
  const float* bv  = (const float*)d_in[6];
  const float* Wp  = (const float*)d_in[7];
  const float* bp  = (const float*)d_in[8];
  const float* gam = (const float*)d_in[9];
  const float* bet = (const float*)d_in[10];
  const float* mea = (const float*)d_in[11];
  const float* var = (const float*)d_in[12];

  unsigned short* wq_b = (unsigned short*)d_ws;
  unsigned short* wk_b = wq_b + 147456;
  unsigned short* wv_b = wk_b + 147456;
  unsigned short* wp_b = wv_b + 147456;
  unsigned short* xb   = wp_b + 147456;          // [12544][384]
  unsigned short* x_b  = xb + 12544 * 384;       // [3136][384]
  unsigned short* q_b  = x_b + 3136 * 384;       // [12544][384]
  unsigned short* k_b  = q_b + 12544 * 384;      // [3136][384]
  unsigned short* vt_b = k_b + 3136 * 384;       // [4][12][32][784]
  unsigned short* o_b  = vt_b + 3136 * 384;      // [12544][384]

  castw_kernel<<<144, 256, 0, stream>>>(Wq, Wk, Wv, Wp, wq_b, wk_b, wv_b, wp_b);
  castx_kernel<<<4704, 256, 0, stream>>>(x, xb);
  poolbn_kernel<<<1176, 256, 0, stream>>>(x, gam, bet, mea, var, x_b);
  gemm_bt<0><<<dim3(98, 3), 256, 0, stream>>>(xb, wq_b, bq, (void*)q_b, 12544);
  gemm_bt<0><<<dim3(25, 3), 256, 0, stream>>>(x_b, wk_b, bk, (void*)k_b, 3136);
  gemm_bt<1><<<dim3(25, 3), 256, 0, stream>>>(x_b, wv_b, bv, (void*)vt_b, 3136);
  attn_kernel<<<2352, 256, 0, stream>>>(q_b, k_b, vt_b, o_b);
  gemm_bt<2><<<dim3(98, 3), 256, 0, stream>>>(o_b, wp_b, bp, d_out, 12544);
}

// Round 3
// 110.615 us; speedup vs baseline: 1.6971x; 1.6971x over previous
//
#include <hip/hip_runtime.h>

// E-MHSA (PVT-style spatial-reduction attention), MI355X/gfx950.
// B=4, N=3136, C=384, H=12, d=32, SR=2 -> Nk=784.
// R3 = R2 + compile fix ((float*)d_out): conflict-free [chunk][row] LDS
// layouts, no-max softmax w/ ones-MFMA rowsum, 2-phase pipelined staging
// (counted vmcnt + raw barriers), fused prep + fused qkv launch. 4 launches.

typedef __bf16 bf16x8 __attribute__((ext_vector_type(8)));
typedef unsigned short u16x8 __attribute__((ext_vector_type(8)));
typedef float f32x4 __attribute__((ext_vector_type(4)));

#define NTOK 3136
#define NKV 784
#define CCH 384
#define SC2 0.25503472078024693f   // 32^-0.5 * log2(e)

__device__ __forceinline__ unsigned short f2b(float f) {
  union { float f; unsigned u; } v; v.f = f;
  unsigned r = v.u + 0x7fffu + ((v.u >> 16) & 1u);   // RNE
  return (unsigned short)(r >> 16);
}

__device__ __forceinline__ bf16x8 ldsb8(const unsigned short* p) {
  u16x8 v = *(const u16x8*)p;
  return __builtin_bit_cast(bf16x8, v);
}

// async global->LDS, 16B/lane; LDS dest = wave-uniform base + lane*16
__device__ __forceinline__ void gload16(const void* g, void* lds) {
  auto* g1 = reinterpret_cast<const __attribute__((address_space(1))) unsigned int*>(
      reinterpret_cast<uintptr_t>(g));
  auto* l3 = reinterpret_cast<__attribute__((address_space(3))) unsigned int*>(
      reinterpret_cast<uintptr_t>(lds));
  __builtin_amdgcn_global_load_lds(g1, l3, 16, 0, 0);
}

// ---------------- fused prep: cast x, pool+BN, cast weights ----------------
// blocks [0,1176): pool+bn+cast-x ; blocks [1176,1320): cast 4 weight mats
__global__ __launch_bounds__(256) void prep_kernel(
    const float* __restrict__ x, const float* __restrict__ gam,
    const float* __restrict__ bet, const float* __restrict__ mea,
    const float* __restrict__ var,
    const float* __restrict__ Wq, const float* __restrict__ Wk,
    const float* __restrict__ Wv, const float* __restrict__ Wp,
    unsigned short* __restrict__ xb, unsigned short* __restrict__ xpb,
    unsigned short* __restrict__ wq, unsigned short* __restrict__ wk,
    unsigned short* __restrict__ wv, unsigned short* __restrict__ wp) {
  int bid = blockIdx.x;
  if (bid < 1176) {
    int i = bid * 256 + threadIdx.x;       // < 301056 = 4*784*96
    int c4 = i % 96;
    int row = i / 96;                      // b*784 + nk
    int b = row / NKV, nk = row - b * NKV;
    const float4* x4 = (const float4*)x;
    size_t base = ((size_t)(b * NTOK + nk * 4)) * 96 + c4;
    float sx = 0.f, sy = 0.f, sz = 0.f, sw = 0.f;
#pragma unroll
    for (int r = 0; r < 4; ++r) {
      float4 v = x4[base + (size_t)r * 96];
      ushort4 cv; cv.x = f2b(v.x); cv.y = f2b(v.y); cv.z = f2b(v.z); cv.w = f2b(v.w);
      ((ushort4*)xb)[base + (size_t)r * 96] = cv;
      sx += v.x; sy += v.y; sz += v.z; sw += v.w;
    }
    float4 g4 = ((const float4*)gam)[c4];
    float4 b4 = ((const float4*)bet)[c4];
    float4 m4 = ((const float4*)mea)[c4];
    float4 v4 = ((const float4*)var)[c4];
    ushort4 r4;
    r4.x = f2b((sx * 0.25f - m4.x) * rsqrtf(v4.x + 1e-5f) * g4.x + b4.x);
    r4.y = f2b((sy * 0.25f - m4.y) * rsqrtf(v4.y + 1e-5f) * g4.y + b4.y);
    r4.z = f2b((sz * 0.25f - m4.z) * rsqrtf(v4.z + 1e-5f) * g4.z + b4.z);
    r4.w = f2b((sw * 0.25f - m4.w) * rsqrtf(v4.w + 1e-5f) * g4.w + b4.w);
    ((ushort4*)xpb)[i] = r4;
  } else {
    int i = (bid - 1176) * 256 + threadIdx.x;   // < 36864 = 147456/4
    float4 va = ((const float4*)Wq)[i];
    float4 vb = ((const float4*)Wk)[i];
    float4 vc = ((const float4*)Wv)[i];
    float4 vd = ((const float4*)Wp)[i];
    ushort4 ra; ra.x = f2b(va.x); ra.y = f2b(va.y); ra.z = f2b(va.z); ra.w = f2b(va.w);
    ushort4 rb; rb.x = f2b(vb.x); rb.y = f2b(vb.y); rb.z = f2b(vb.z); rb.w = f2b(vb.w);
    ushort4 rc; rc.x = f2b(vc.x); rc.y = f2b(vc.y); rc.z = f2b(vc.z); rc.w = f2b(vc.w);
    ushort4 rd; rd.x = f2b(vd.x); rd.y = f2b(vd.y); rd.z = f2b(vd.z); rd.w = f2b(vd.w);
    ((ushort4*)wq)[i] = ra; ((ushort4*)wk)[i] = rb;
    ((ushort4*)wv)[i] = rc; ((ushort4*)wp)[i] = rd;
  }
}

// ---------------- GEMM body: C[64 x 128] = A[64xK] * W[128 cols][K]^T + bias --
// LDS layout [kchunk][row] 16B units -> conflict-free ds_read_b128.
// 2-phase pipeline: stage kk+1, compute kk, vmcnt(0)+s_barrier once per step.
// epi: 0 bf16 row-major, 1 bf16 scatter vt[b][h][d][j], 2 fp32 row-major.
__device__ __forceinline__ void gemm_body(
    const unsigned short* __restrict__ A, const unsigned short* __restrict__ Bt,
    const float* __restrict__ bias, void* __restrict__ out,
    int row0, int col0, int epi,
    unsigned short (*sA)[2048], unsigned short (*sB)[4096]) {
  const int t = threadIdx.x, w = t >> 6, l = t & 63;
  const int wr = w >> 1, wc = w & 1;

  f32x4 acc[2][4];
#pragma unroll
  for (int m = 0; m < 2; ++m)
#pragma unroll
    for (int n = 0; n < 4; ++n) acc[m][n] = (f32x4){0.f, 0.f, 0.f, 0.f};

  auto STAGE = [&](int kk, int bsel) {
    gload16(A + (size_t)(row0 + l) * CCH + kk * 32 + w * 8,
            (char*)sA[bsel] + w * 1024);
    gload16(Bt + (size_t)(col0 + l) * CCH + kk * 32 + w * 8,
            (char*)sB[bsel] + w * 2048);
    gload16(Bt + (size_t)(col0 + 64 + l) * CCH + kk * 32 + w * 8,
            (char*)sB[bsel] + w * 2048 + 1024);
  };

  STAGE(0, 0);
  asm volatile("s_waitcnt vmcnt(0)" ::: "memory");
  __builtin_amdgcn_s_barrier();

  for (int kk = 0; kk < 12; ++kk) {
    const int cur = kk & 1;
    if (kk < 11) STAGE(kk + 1, cur ^ 1);
    bf16x8 af[2], bfv[4];
#pragma unroll
    for (int m = 0; m < 2; ++m)
      af[m] = ldsb8(&sA[cur][(l >> 4) * 512 + (wr * 32 + m * 16 + (l & 15)) * 8]);
#pragma unroll
    for (int n = 0; n < 4; ++n)
      bfv[n] = ldsb8(&sB[cur][(l >> 4) * 1024 + (wc * 64 + n * 16 + (l & 15)) * 8]);
#pragma unroll
    for (int m = 0; m < 2; ++m)
#pragma unroll
      for (int n = 0; n < 4; ++n)
        acc[m][n] = __builtin_amdgcn_mfma_f32_16x16x32_bf16(af[m], bfv[n], acc[m][n], 0, 0, 0);
    if (kk < 11) {
      asm volatile("s_waitcnt vmcnt(0)" ::: "memory");
      __builtin_amdgcn_s_barrier();
    }
  }

#pragma unroll
  for (int m = 0; m < 2; ++m) {
#pragma unroll
    for (int r = 0; r < 4; ++r) {
      int row = row0 + wr * 32 + m * 16 + (l >> 4) * 4 + r;
#pragma unroll
      for (int n = 0; n < 4; ++n) {
        int col = col0 + wc * 64 + n * 16 + (l & 15);
        float v = acc[m][n][r] + bias[col];
        if (epi == 0) {
          ((unsigned short*)out)[(size_t)row * CCH + col] = f2b(v);
        } else if (epi == 2) {
          ((float*)out)[(size_t)row * CCH + col] = v;
        } else {
          int b_ = row / NKV, j = row - b_ * NKV;
          int h_ = col >> 5, d = col & 31;
          ((unsigned short*)out)[((size_t)((b_ * 12 + h_) * 32 + d)) * NKV + j] = f2b(v);
        }
      }
    }
  }
}

// fused q/k/v projection: grid.x = 196(q) + 49(k) + 49(v), grid.y = 3 col-blocks
__global__ __launch_bounds__(256) void qkv_kernel(
    const unsigned short* __restrict__ xb, const unsigned short* __restrict__ xpb,
    const unsigned short* __restrict__ wq, const unsigned short* __restrict__ wk,
    const unsigned short* __restrict__ wv,
    const float* __restrict__ bq, const float* __restrict__ bk,
    const float* __restrict__ bv,
    unsigned short* __restrict__ q_b, unsigned short* __restrict__ k_b,
    unsigned short* __restrict__ vt_b) {
  __shared__ unsigned short sA[2][2048];
  __shared__ unsigned short sB[2][4096];
  int bx = blockIdx.x;
  const unsigned short *Ap, *Wp_;
  const float* bp_;
  void* op;
  int epi, row0;
  if (bx < 196)      { Ap = xb;  Wp_ = wq; bp_ = bq; op = q_b;  epi = 0; row0 = bx * 64; }
  else if (bx < 245) { Ap = xpb; Wp_ = wk; bp_ = bk; op = k_b;  epi = 0; row0 = (bx - 196) * 64; }
  else               { Ap = xpb; Wp_ = wv; bp_ = bv; op = vt_b; epi = 1; row0 = (bx - 245) * 64; }
  gemm_body(Ap, Wp_, bp_, op, row0, blockIdx.y * 128, epi, sA, sB);
}

__global__ __launch_bounds__(256) void outproj_kernel(
    const unsigned short* __restrict__ ob, const unsigned short* __restrict__ wp,
    const float* __restrict__ bp_, float* __restrict__ out) {
  __shared__ unsigned short sA[2][2048];
  __shared__ unsigned short sB[2][4096];
  gemm_body(ob, wp, bp_, (void*)out, blockIdx.x * 64, blockIdx.y * 128, 2, sA, sB);
}

// ---------------- flash attention (no-max softmax) ----------------
// grid: b*H*(N/64). 4 waves, wave w owns q rows [q0+16w, q0+16w+16).
// KV tiles of 64 (13 tiles; tail cols masked to 784). Rowsum via ones-MFMA.
__global__ __launch_bounds__(256) void attn_kernel(
    const unsigned short* __restrict__ qb, const unsigned short* __restrict__ kb,
    const unsigned short* __restrict__ vtb, unsigned short* __restrict__ ob) {
  __shared__ unsigned short sQ[2048];       // [4 kchunk][64 qrow] x8
  __shared__ unsigned short sK[2][2048];    // [4 kchunk][64 j] x8
  __shared__ unsigned short sV[2][2048];    // [8 jchunk][32 d] x8
  __shared__ unsigned short sP[4][1024];    // per-wave, XOR-swizzled units

  const int bx = blockIdx.x;
  const int qt = bx % 49;
  const int h = (bx / 49) % 12;
  const int b = bx / 588;
  const int t = threadIdx.x, w = t >> 6, l = t & 63;
  const int q0 = qt * 64;

  auto stageKV = [&](int ttile, int bsel) {
    int j0s = ttile * 64;
    int j = j0s + l; if (j > NKV - 1) j = NKV - 1;
    gload16(kb + ((size_t)(b * NKV + j)) * CCH + h * 32 + w * 8,
            (char*)sK[bsel] + w * 1024);
    int jc = j0s + (2 * w + (l >> 5)) * 8; if (jc > NKV - 8) jc = NKV - 8;
    gload16(vtb + ((size_t)((b * 12 + h) * 32 + (l & 31))) * NKV + jc,
            (char*)sV[bsel] + w * 1024);
  };

  // prologue: Q + tile 0
  gload16(qb + ((size_t)(b * NTOK + q0 + l)) * CCH + h * 32 + w * 8,
          (char*)sQ + w * 1024);
  stageKV(0, 0);
  asm volatile("s_waitcnt vmcnt(0)" ::: "memory");
  __builtin_amdgcn_s_barrier();

  const bf16x8 aq = ldsb8(&sQ[(l >> 4) * 512 + (w * 16 + (l & 15)) * 8]);
  bf16x8 ones;
#pragma unroll
  for (int i = 0; i < 8; ++i) ones[i] = (__bf16)1.0f;

  f32x4 acc0 = (f32x4){0.f, 0.f, 0.f, 0.f};
  f32x4 acc1 = (f32x4){0.f, 0.f, 0.f, 0.f};
  f32x4 accl = (f32x4){0.f, 0.f, 0.f, 0.f};
  unsigned short* sPw = sP[w];
  const int g4 = (l >> 4) * 4;
  const int qr = l & 15;
  const int rkey = (qr & 7) ^ ((qr >> 3) << 1);   // read-side XOR key

  for (int tt = 0; tt < 13; ++tt) {
    const int cur = tt & 1;
    if (tt < 12) stageKV(tt + 1, cur ^ 1);

    // QK^T: s[n] covers kv cols n*16+(l&15), q rows g4..g4+3
    f32x4 s[4];
#pragma unroll
    for (int n = 0; n < 4; ++n) {
      bf16x8 kf = ldsb8(&sK[cur][(l >> 4) * 512 + (n * 16 + (l & 15)) * 8]);
      s[n] = __builtin_amdgcn_mfma_f32_16x16x32_bf16(aq, kf, (f32x4){0.f, 0.f, 0.f, 0.f}, 0, 0, 0);
    }

    float p[4][4];
#pragma unroll
    for (int n = 0; n < 4; ++n)
#pragma unroll
      for (int r = 0; r < 4; ++r) p[n][r] = exp2f(s[n][r] * SC2);
    if (tt == 12) {
#pragma unroll
      for (int n = 0; n < 4; ++n)
        if (768 + n * 16 + (l & 15) >= NKV)
#pragma unroll
          for (int r = 0; r < 4; ++r) p[n][r] = 0.f;
    }

    // P -> per-wave LDS, swizzled: unit(row,cc) = row*8 + (cc ^ row&7 ^ (row>>3)<<1)
#pragma unroll
    for (int n = 0; n < 4; ++n) {
      int cc = 2 * n + ((l >> 3) & 1);
#pragma unroll
      for (int r = 0; r < 4; ++r) {
        int qrow = g4 + r;
        int swz = (cc ^ (qrow & 7) ^ ((qrow >> 3) << 1)) & 7;
        sPw[qrow * 64 + swz * 8 + (l & 7)] = f2b(p[n][r]);
      }
    }

    // PV + rowsum
#pragma unroll
    for (int kkk = 0; kkk < 2; ++kkk) {
      int ccr = kkk * 4 + (l >> 4);
      int swzr = (ccr ^ rkey) & 7;
      bf16x8 pa = ldsb8(&sPw[qr * 64 + swzr * 8]);
      bf16x8 v0 = ldsb8(&sV[cur][(kkk * 4 + (l >> 4)) * 256 + (l & 15) * 8]);
      bf16x8 v1 = ldsb8(&sV[cur][(kkk * 4 + (l >> 4)) * 256 + (16 + (l & 15)) * 8]);
      acc0 = __builtin_amdgcn_mfma_f32_16x16x32_bf16(pa, v0, acc0, 0, 0, 0);
      acc1 = __builtin_amdgcn_mfma_f32_16x16x32_bf16(pa, v1, acc1, 0, 0, 0);
      accl = __builtin_amdgcn_mfma_f32_16x16x32_bf16(pa, ones, accl, 0, 0, 0);
    }

    if (tt < 12) {
      asm volatile("s_waitcnt vmcnt(0)" ::: "memory");
      __builtin_amdgcn_s_barrier();
    }
  }

#pragma unroll
  for (int r = 0; r < 4; ++r) {
    int row = q0 + w * 16 + g4 + r;
    float inv = 1.f / accl[r];
    size_t base = ((size_t)(b * NTOK + row)) * CCH + h * 32;
    ob[base + (l & 15)] = f2b(acc0[r] * inv);
    ob[base + 16 + (l & 15)] = f2b(acc1[r] * inv);
  }
}

// ---------------- launch ----------------

extern "C" void kernel_launch(void* const* d_in, const int* in_sizes, int n_in,
                              void* d_out, int out_size, void* d_ws, size_t ws_size,
                              hipStream_t stream) {
  const float* x   = (const float*)d_in[0];
  const float* Wq  = (const float*)d_in[1];
  const float* bq  = (const float*)d_in[2];
  const float* Wk  = (const float*)d_in[3];
  const float* bk  = (const float*)d_in[4];
  const float* Wv  = (const float*)d_in[5];
  const float* bv  = (const float*)d_in[6];
  const float* Wp  = (const float*)d_in[7];
  const float* bp  = (const float*)d_in[8];
  const float* gam = (const float*)d_in[9];
  const float* bet = (const float*)d_in[10];
  const float* mea = (const float*)d_in[11];
  const float* var = (const float*)d_in[12];

  unsigned short* wq_b = (unsigned short*)d_ws;
  unsigned short* wk_b = wq_b + 147456;
  unsigned short* wv_b = wk_b + 147456;
  unsigned short* wp_b = wv_b + 147456;
  unsigned short* xb   = wp_b + 147456;          // [12544][384]
  unsigned short* x_b  = xb + 12544 * 384;       // [3136][384]
  unsigned short* q_b  = x_b + 3136 * 384;       // [12544][384]
  unsigned short* k_b  = q_b + 12544 * 384;      // [3136][384]
  unsigned short* vt_b = k_b + 3136 * 384;       // [4][12][32][784]
  unsigned short* o_b  = vt_b + 3136 * 384;      // [12544][384]

  prep_kernel<<<1320, 256, 0, stream>>>(x, gam, bet, mea, var, Wq, Wk, Wv, Wp,
                                        xb, x_b, wq_b, wk_b, wv_b, wp_b);
  qkv_kernel<<<dim3(294, 3), 256, 0, stream>>>(xb, x_b, wq_b, wk_b, wv_b,
                                               bq, bk, bv, q_b, k_b, vt_b);
  attn_kernel<<<2352, 256, 0, stream>>>(q_b, k_b, vt_b, o_b);
  outproj_kernel<<<dim3(196, 3), 256, 0, stream>>>(o_b, wp_b, bp, (float*)d_out);
}

// Round 4
// 95.513 us; speedup vs baseline: 1.9654x; 1.1581x over previous
//
#include <hip/hip_runtime.h>

// E-MHSA (PVT-style spatial-reduction attention), MI355X/gfx950.
// B=4, N=3136, C=384, H=12, d=32, SR=2 -> Nk=784.
// R4: attn VALU cut — κ-permuted P/V (kv permuted within each 64-tile so
// P packs as ds_write_b64 of cvt_pk'd bf16x4), scale*log2e folded into Q
// projection, raw v_exp_f32. V buffer κ-laid-out [b][h][d][832], pad zeroed.

typedef __bf16 bf16x8 __attribute__((ext_vector_type(8)));
typedef __bf16 bf16x4 __attribute__((ext_vector_type(4)));
typedef unsigned short u16x8 __attribute__((ext_vector_type(8)));
typedef float f32x4 __attribute__((ext_vector_type(4)));

#define NTOK 3136
#define NKV 784
#define CCH 384
#define KPAD 832                   // 13 * 64, κ-row stride for vt
#define SC2 0.25503472078024693f   // 32^-0.5 * log2(e), folded into Q

__device__ __forceinline__ unsigned short f2b(float f) {
  union { float f; unsigned u; } v; v.f = f;
  unsigned r = v.u + 0x7fffu + ((v.u >> 16) & 1u);   // RNE
  return (unsigned short)(r >> 16);
}

__device__ __forceinline__ bf16x8 ldsb8(const unsigned short* p) {
  u16x8 v = *(const u16x8*)p;
  return __builtin_bit_cast(bf16x8, v);
}

// async global->LDS, 16B/lane; LDS dest = wave-uniform base + lane*16
__device__ __forceinline__ void gload16(const void* g, void* lds) {
  auto* g1 = reinterpret_cast<const __attribute__((address_space(1))) unsigned int*>(
      reinterpret_cast<uintptr_t>(g));
  auto* l3 = reinterpret_cast<__attribute__((address_space(3))) unsigned int*>(
      reinterpret_cast<uintptr_t>(lds));
  __builtin_amdgcn_global_load_lds(g1, l3, 16, 0, 0);
}

// ---------------- fused prep ----------------
// [0,1176): pool+bn + cast-x ; [1176,1320): cast weights ; [1320,1416): zero vt pad
__global__ __launch_bounds__(256) void prep_kernel(
    const float* __restrict__ x, const float* __restrict__ gam,
    const float* __restrict__ bet, const float* __restrict__ mea,
    const float* __restrict__ var,
    const float* __restrict__ Wq, const float* __restrict__ Wk,
    const float* __restrict__ Wv, const float* __restrict__ Wp,
    unsigned short* __restrict__ xb, unsigned short* __restrict__ xpb,
    unsigned short* __restrict__ wq, unsigned short* __restrict__ wk,
    unsigned short* __restrict__ wv, unsigned short* __restrict__ wp,
    unsigned short* __restrict__ vt) {
  int bid = blockIdx.x;
  if (bid < 1176) {
    int i = bid * 256 + threadIdx.x;       // < 301056 = 4*784*96
    int c4 = i % 96;
    int row = i / 96;                      // b*784 + nk
    int b = row / NKV, nk = row - b * NKV;
    const float4* x4 = (const float4*)x;
    size_t base = ((size_t)(b * NTOK + nk * 4)) * 96 + c4;
    float sx = 0.f, sy = 0.f, sz = 0.f, sw = 0.f;
#pragma unroll
    for (int r = 0; r < 4; ++r) {
      float4 v = x4[base + (size_t)r * 96];
      ushort4 cv; cv.x = f2b(v.x); cv.y = f2b(v.y); cv.z = f2b(v.z); cv.w = f2b(v.w);
      ((ushort4*)xb)[base + (size_t)r * 96] = cv;
      sx += v.x; sy += v.y; sz += v.z; sw += v.w;
    }
    float4 g4 = ((const float4*)gam)[c4];
    float4 b4 = ((const float4*)bet)[c4];
    float4 m4 = ((const float4*)mea)[c4];
    float4 v4 = ((const float4*)var)[c4];
    ushort4 r4;
    r4.x = f2b((sx * 0.25f - m4.x) * rsqrtf(v4.x + 1e-5f) * g4.x + b4.x);
    r4.y = f2b((sy * 0.25f - m4.y) * rsqrtf(v4.y + 1e-5f) * g4.y + b4.y);
    r4.z = f2b((sz * 0.25f - m4.z) * rsqrtf(v4.z + 1e-5f) * g4.z + b4.z);
    r4.w = f2b((sw * 0.25f - m4.w) * rsqrtf(v4.w + 1e-5f) * g4.w + b4.w);
    ((ushort4*)xpb)[i] = r4;
  } else if (bid < 1320) {
    int i = (bid - 1176) * 256 + threadIdx.x;   // < 36864 = 147456/4
    float4 va = ((const float4*)Wq)[i];
    float4 vb = ((const float4*)Wk)[i];
    float4 vc = ((const float4*)Wv)[i];
    float4 vd = ((const float4*)Wp)[i];
    ushort4 ra; ra.x = f2b(va.x); ra.y = f2b(va.y); ra.z = f2b(va.z); ra.w = f2b(va.w);
    ushort4 rb; rb.x = f2b(vb.x); rb.y = f2b(vb.y); rb.z = f2b(vb.z); rb.w = f2b(vb.w);
    ushort4 rc; rc.x = f2b(vc.x); rc.y = f2b(vc.y); rc.z = f2b(vc.z); rc.w = f2b(vc.w);
    ushort4 rd; rd.x = f2b(vd.x); rd.y = f2b(vd.y); rd.z = f2b(vd.z); rd.w = f2b(vd.w);
    ((ushort4*)wq)[i] = ra; ((ushort4*)wk)[i] = rb;
    ((ushort4*)wv)[i] = rc; ((ushort4*)wp)[i] = rd;
  } else {
    // zero vt κ-pad [768,832) for all 1536 (b,h,d) rows
    int i = (bid - 1320) * 256 + threadIdx.x;   // < 24576
    int row = i >> 4, quad = i & 15;
    ushort4 z; z.x = 0; z.y = 0; z.z = 0; z.w = 0;
    *(ushort4*)&vt[(size_t)row * KPAD + 768 + quad * 4] = z;
  }
}

// ---------------- GEMM body: C[64 x 128] = A[64xK] * W[128 cols][K]^T + bias --
// LDS layout [kchunk][row] 16B units -> conflict-free ds_read_b128.
// 2-phase pipeline: stage kk+1, compute kk, vmcnt(0)+s_barrier once per step.
// epi: 0 bf16 row-major (scaled by oscale), 1 bf16 κ-scatter vt, 2 fp32.
__device__ __forceinline__ void gemm_body(
    const unsigned short* __restrict__ A, const unsigned short* __restrict__ Bt,
    const float* __restrict__ bias, void* __restrict__ out,
    int row0, int col0, int epi, float oscale,
    unsigned short (*sA)[2048], unsigned short (*sB)[4096]) {
  const int t = threadIdx.x, w = t >> 6, l = t & 63;
  const int wr = w >> 1, wc = w & 1;

  f32x4 acc[2][4];
#pragma unroll
  for (int m = 0; m < 2; ++m)
#pragma unroll
    for (int n = 0; n < 4; ++n) acc[m][n] = (f32x4){0.f, 0.f, 0.f, 0.f};

  auto STAGE = [&](int kk, int bsel) {
    gload16(A + (size_t)(row0 + l) * CCH + kk * 32 + w * 8,
            (char*)sA[bsel] + w * 1024);
    gload16(Bt + (size_t)(col0 + l) * CCH + kk * 32 + w * 8,
            (char*)sB[bsel] + w * 2048);
    gload16(Bt + (size_t)(col0 + 64 + l) * CCH + kk * 32 + w * 8,
            (char*)sB[bsel] + w * 2048 + 1024);
  };

  STAGE(0, 0);
  asm volatile("s_waitcnt vmcnt(0)" ::: "memory");
  __builtin_amdgcn_s_barrier();

  for (int kk = 0; kk < 12; ++kk) {
    const int cur = kk & 1;
    if (kk < 11) STAGE(kk + 1, cur ^ 1);
    bf16x8 af[2], bfv[4];
#pragma unroll
    for (int m = 0; m < 2; ++m)
      af[m] = ldsb8(&sA[cur][(l >> 4) * 512 + (wr * 32 + m * 16 + (l & 15)) * 8]);
#pragma unroll
    for (int n = 0; n < 4; ++n)
      bfv[n] = ldsb8(&sB[cur][(l >> 4) * 1024 + (wc * 64 + n * 16 + (l & 15)) * 8]);
#pragma unroll
    for (int m = 0; m < 2; ++m)
#pragma unroll
      for (int n = 0; n < 4; ++n)
        acc[m][n] = __builtin_amdgcn_mfma_f32_16x16x32_bf16(af[m], bfv[n], acc[m][n], 0, 0, 0);
    if (kk < 11) {
      asm volatile("s_waitcnt vmcnt(0)" ::: "memory");
      __builtin_amdgcn_s_barrier();
    }
  }

#pragma unroll
  for (int m = 0; m < 2; ++m) {
#pragma unroll
    for (int r = 0; r < 4; ++r) {
      int row = row0 + wr * 32 + m * 16 + (l >> 4) * 4 + r;
#pragma unroll
      for (int n = 0; n < 4; ++n) {
        int col = col0 + wc * 64 + n * 16 + (l & 15);
        float v = (acc[m][n][r] + bias[col]) * oscale;
        if (epi == 0) {
          ((unsigned short*)out)[(size_t)row * CCH + col] =
              __builtin_bit_cast(unsigned short, (__bf16)v);
        } else if (epi == 2) {
          ((float*)out)[(size_t)row * CCH + col] = v;
        } else {
          int b_ = row / NKV, j = row - b_ * NKV;
          int h_ = col >> 5, d = col & 31;
          int loc = j & 63;
          int kap = (j & ~63) + ((loc & 15) << 2) + (loc >> 4);   // κ-permute
          ((unsigned short*)out)[((size_t)((b_ * 12 + h_) * 32 + d)) * KPAD + kap] =
              __builtin_bit_cast(unsigned short, (__bf16)v);
        }
      }
    }
  }
}

// fused q/k/v projection: grid.x = 196(q) + 49(k) + 49(v), grid.y = 3 col-blocks
__global__ __launch_bounds__(256) void qkv_kernel(
    const unsigned short* __restrict__ xb, const unsigned short* __restrict__ xpb,
    const unsigned short* __restrict__ wq, const unsigned short* __restrict__ wk,
    const unsigned short* __restrict__ wv,
    const float* __restrict__ bq, const float* __restrict__ bk,
    const float* __restrict__ bv,
    unsigned short* __restrict__ q_b, unsigned short* __restrict__ k_b,
    unsigned short* __restrict__ vt_b) {
  __shared__ unsigned short sA[2][2048];
  __shared__ unsigned short sB[2][4096];
  int bx = blockIdx.x;
  const unsigned short *Ap, *Wp_;
  const float* bp_;
  void* op;
  int epi, row0;
  float osc;
  if (bx < 196)      { Ap = xb;  Wp_ = wq; bp_ = bq; op = q_b;  epi = 0; row0 = bx * 64;         osc = SC2; }
  else if (bx < 245) { Ap = xpb; Wp_ = wk; bp_ = bk; op = k_b;  epi = 0; row0 = (bx - 196) * 64; osc = 1.f; }
  else               { Ap = xpb; Wp_ = wv; bp_ = bv; op = vt_b; epi = 1; row0 = (bx - 245) * 64; osc = 1.f; }
  gemm_body(Ap, Wp_, bp_, op, row0, blockIdx.y * 128, epi, osc, sA, sB);
}

__global__ __launch_bounds__(256) void outproj_kernel(
    const unsigned short* __restrict__ ob, const unsigned short* __restrict__ wp,
    const float* __restrict__ bp_, float* __restrict__ out) {
  __shared__ unsigned short sA[2][2048];
  __shared__ unsigned short sB[2][4096];
  gemm_body(ob, wp, bp_, (void*)out, blockIdx.x * 64, blockIdx.y * 128, 2, 1.f, sA, sB);
}

// ---------------- flash attention (no-max softmax, κ-permuted P/V) ----------
// grid: b*H*(N/64). 4 waves, wave w owns q rows [q0+16w, q0+16w+16).
// KV tiles of 64 (13; tail masked). Rowsum via ones-MFMA. Q pre-scaled.
__global__ __launch_bounds__(256) void attn_kernel(
    const unsigned short* __restrict__ qb, const unsigned short* __restrict__ kb,
    const unsigned short* __restrict__ vtb, unsigned short* __restrict__ ob) {
  __shared__ unsigned short sQ[2048];       // [4 kchunk][64 qrow] x8
  __shared__ unsigned short sK[2][2048];    // [4 kchunk][64 j] x8
  __shared__ unsigned short sV[2][2048];    // [8 κchunk][32 d] x8
  __shared__ unsigned short sP[4][1024];    // per-wave [16 q][8 u' x8], XOR-swz

  const int bx = blockIdx.x;
  const int qt = bx % 49;
  const int h = (bx / 49) % 12;
  const int b = bx / 588;
  const int t = threadIdx.x, w = t >> 6, l = t & 63;
  const int q0 = qt * 64;
  const int hi = l >> 4, c = l & 15;

  auto stageKV = [&](int ttile, int bsel) {
    int j = ttile * 64 + l; if (j > NKV - 1) j = NKV - 1;
    gload16(kb + ((size_t)(b * NKV + j)) * CCH + h * 32 + w * 8,
            (char*)sK[bsel] + w * 1024);
    int kap = ttile * 64 + (2 * w + (l >> 5)) * 8;   // κ index, KPAD row = no OOB
    gload16(vtb + ((size_t)((b * 12 + h) * 32 + (l & 31))) * KPAD + kap,
            (char*)sV[bsel] + w * 1024);
  };

  // prologue: Q + tile 0
  gload16(qb + ((size_t)(b * NTOK + q0 + l)) * CCH + h * 32 + w * 8,
          (char*)sQ + w * 1024);
  stageKV(0, 0);
  asm volatile("s_waitcnt vmcnt(0)" ::: "memory");
  __builtin_amdgcn_s_barrier();

  const bf16x8 aq = ldsb8(&sQ[hi * 512 + (w * 16 + c) * 8]);
  bf16x8 ones;
#pragma unroll
  for (int i = 0; i < 8; ++i) ones[i] = (__bf16)1.0f;

  f32x4 acc0 = (f32x4){0.f, 0.f, 0.f, 0.f};
  f32x4 acc1 = (f32x4){0.f, 0.f, 0.f, 0.f};
  f32x4 accl = (f32x4){0.f, 0.f, 0.f, 0.f};
  unsigned short* sPw = sP[w];

  for (int tt = 0; tt < 13; ++tt) {
    const int cur = tt & 1;
    if (tt < 12) stageKV(tt + 1, cur ^ 1);

    // QK^T (Q pre-scaled by 32^-.5*log2e): s[n] = scores, q rows hi*4..+3,
    // kv col n*16+c
    f32x4 s[4];
#pragma unroll
    for (int n = 0; n < 4; ++n) {
      bf16x8 kf = ldsb8(&sK[cur][hi * 512 + (n * 16 + c) * 8]);
      s[n] = __builtin_amdgcn_mfma_f32_16x16x32_bf16(aq, kf, (f32x4){0.f, 0.f, 0.f, 0.f}, 0, 0, 0);
    }

    float p[4][4];
#pragma unroll
    for (int n = 0; n < 4; ++n)
#pragma unroll
      for (int r = 0; r < 4; ++r) {
        float e;
        asm("v_exp_f32 %0, %1" : "=v"(e) : "v"(s[n][r]));
        p[n][r] = e;
      }
    if (tt == 12) {   // kv = 768 + n*16 + c valid only for n==0
#pragma unroll
      for (int n = 1; n < 4; ++n)
#pragma unroll
        for (int r = 0; r < 4; ++r) p[n][r] = 0.f;
    }

    // P -> per-wave LDS, κ = c*4 + n; one b64 write per r (κ0 = 4c).
    // unit u = c>>1 swizzled u' = u ^ (qrow&7); in-unit half = c&1.
#pragma unroll
    for (int r = 0; r < 4; ++r) {
      int qrow = hi * 4 + r;
      int up = (c >> 1) ^ (qrow & 7);
      bf16x4 pk;
      pk[0] = (__bf16)p[0][r]; pk[1] = (__bf16)p[1][r];
      pk[2] = (__bf16)p[2][r]; pk[3] = (__bf16)p[3][r];
      *(bf16x4*)&sPw[qrow * 64 + up * 8 + (c & 1) * 4] = pk;
    }

    // PV + rowsum: A-frag lane (q=c) needs κ = kkk*32 + hi*8 .. +8
#pragma unroll
    for (int kkk = 0; kkk < 2; ++kkk) {
      int ur = (kkk * 4 + hi) ^ (c & 7);
      bf16x8 pa = ldsb8(&sPw[c * 64 + ur * 8]);
      bf16x8 v0 = ldsb8(&sV[cur][(kkk * 4 + hi) * 256 + c * 8]);
      bf16x8 v1 = ldsb8(&sV[cur][(kkk * 4 + hi) * 256 + (16 + c) * 8]);
      acc0 = __builtin_amdgcn_mfma_f32_16x16x32_bf16(pa, v0, acc0, 0, 0, 0);
      acc1 = __builtin_amdgcn_mfma_f32_16x16x32_bf16(pa, v1, acc1, 0, 0, 0);
      accl = __builtin_amdgcn_mfma_f32_16x16x32_bf16(pa, ones, accl, 0, 0, 0);
    }

    if (tt < 12) {
      asm volatile("s_waitcnt vmcnt(0)" ::: "memory");
      __builtin_amdgcn_s_barrier();
    }
  }

#pragma unroll
  for (int r = 0; r < 4; ++r) {
    int row = q0 + w * 16 + hi * 4 + r;
    float inv = 1.f / accl[r];
    size_t base = ((size_t)(b * NTOK + row)) * CCH + h * 32;
    ob[base + c] = __builtin_bit_cast(unsigned short, (__bf16)(acc0[r] * inv));
    ob[base + 16 + c] = __builtin_bit_cast(unsigned short, (__bf16)(acc1[r] * inv));
  }
}

// ---------------- launch ----------------

extern "C" void kernel_launch(void* const* d_in, const int* in_sizes, int n_in,
                              void* d_out, int out_size, void* d_ws, size_t ws_size,
                              hipStream_t stream) {
  const float* x   = (const float*)d_in[0];
  const float* Wq  = (const float*)d_in[1];
  const float* bq  = (const float*)d_in[2];
  const float* Wk  = (const float*)d_in[3];
  const float* bk  = (const float*)d_in[4];
  const float* Wv  = (const float*)d_in[5];
  const float* bv  = (const float*)d_in[6];
  const float* Wp  = (const float*)d_in[7];
  const float* bp  = (const float*)d_in[8];
  const float* gam = (const float*)d_in[9];
  const float* bet = (const float*)d_in[10];
  const float* mea = (const float*)d_in[11];
  const float* var = (const float*)d_in[12];

  unsigned short* wq_b = (unsigned short*)d_ws;
  unsigned short* wk_b = wq_b + 147456;
  unsigned short* wv_b = wk_b + 147456;
  unsigned short* wp_b = wv_b + 147456;
  unsigned short* xb   = wp_b + 147456;          // [12544][384]
  unsigned short* x_b  = xb + 12544 * 384;       // [3136][384]
  unsigned short* q_b  = x_b + 3136 * 384;       // [12544][384] (pre-scaled)
  unsigned short* k_b  = q_b + 12544 * 384;      // [3136][384]
  unsigned short* vt_b = k_b + 3136 * 384;       // [4][12][32][832] κ-permuted
  unsigned short* o_b  = vt_b + 1536 * KPAD;     // [12544][384]

  prep_kernel<<<1416, 256, 0, stream>>>(x, gam, bet, mea, var, Wq, Wk, Wv, Wp,
                                        xb, x_b, wq_b, wk_b, wv_b, wp_b, vt_b);
  qkv_kernel<<<dim3(294, 3), 256, 0, stream>>>(xb, x_b, wq_b, wk_b, wv_b,
                                               bq, bk, bv, q_b, k_b, vt_b);
  attn_kernel<<<2352, 256, 0, stream>>>(q_b, k_b, vt_b, o_b);
  outproj_kernel<<<dim3(196, 3), 256, 0, stream>>>(o_b, wp_b, bp, (float*)d_out);
}

// Round 5
// 94.586 us; speedup vs baseline: 1.9847x; 1.0098x over previous
//
#include <hip/hip_runtime.h>

// E-MHSA (PVT-style spatial-reduction attention), MI355X/gfx950.
// B=4, N=3136, C=384, H=12, d=32, SR=2 -> Nk=784.
// R5: attn P kept fully in registers — swapped QK^T (mfma(K,Q) so each lane
// holds P[q=c][kv=n*16+hi*4+r]) + κ'-permuted V (κ' = (n&1)*32+hi*8+(n>>1)*4+r)
// so lane-local packed P IS the PV A-fragment. No P LDS traffic at all.

typedef __bf16 bf16x8 __attribute__((ext_vector_type(8)));
typedef unsigned short u16x8 __attribute__((ext_vector_type(8)));
typedef float f32x4 __attribute__((ext_vector_type(4)));

#define NTOK 3136
#define NKV 784
#define CCH 384
#define KPAD 832                   // 13 * 64, κ-row stride for vt
#define SC2 0.25503472078024693f   // 32^-0.5 * log2(e), folded into Q

__device__ __forceinline__ unsigned short f2b(float f) {
  union { float f; unsigned u; } v; v.f = f;
  unsigned r = v.u + 0x7fffu + ((v.u >> 16) & 1u);   // RNE
  return (unsigned short)(r >> 16);
}

__device__ __forceinline__ bf16x8 ldsb8(const unsigned short* p) {
  u16x8 v = *(const u16x8*)p;
  return __builtin_bit_cast(bf16x8, v);
}

// async global->LDS, 16B/lane; LDS dest = wave-uniform base + lane*16
__device__ __forceinline__ void gload16(const void* g, void* lds) {
  auto* g1 = reinterpret_cast<const __attribute__((address_space(1))) unsigned int*>(
      reinterpret_cast<uintptr_t>(g));
  auto* l3 = reinterpret_cast<__attribute__((address_space(3))) unsigned int*>(
      reinterpret_cast<uintptr_t>(lds));
  __builtin_amdgcn_global_load_lds(g1, l3, 16, 0, 0);
}

// ---------------- fused prep ----------------
// [0,1176): pool+bn + cast-x ; [1176,1320): cast weights ; [1320,1416): zero vt pad
__global__ __launch_bounds__(256) void prep_kernel(
    const float* __restrict__ x, const float* __restrict__ gam,
    const float* __restrict__ bet, const float* __restrict__ mea,
    const float* __restrict__ var,
    const float* __restrict__ Wq, const float* __restrict__ Wk,
    const float* __restrict__ Wv, const float* __restrict__ Wp,
    unsigned short* __restrict__ xb, unsigned short* __restrict__ xpb,
    unsigned short* __restrict__ wq, unsigned short* __restrict__ wk,
    unsigned short* __restrict__ wv, unsigned short* __restrict__ wp,
    unsigned short* __restrict__ vt) {
  int bid = blockIdx.x;
  if (bid < 1176) {
    int i = bid * 256 + threadIdx.x;       // < 301056 = 4*784*96
    int c4 = i % 96;
    int row = i / 96;                      // b*784 + nk
    int b = row / NKV, nk = row - b * NKV;
    const float4* x4 = (const float4*)x;
    size_t base = ((size_t)(b * NTOK + nk * 4)) * 96 + c4;
    float sx = 0.f, sy = 0.f, sz = 0.f, sw = 0.f;
#pragma unroll
    for (int r = 0; r < 4; ++r) {
      float4 v = x4[base + (size_t)r * 96];
      ushort4 cv; cv.x = f2b(v.x); cv.y = f2b(v.y); cv.z = f2b(v.z); cv.w = f2b(v.w);
      ((ushort4*)xb)[base + (size_t)r * 96] = cv;
      sx += v.x; sy += v.y; sz += v.z; sw += v.w;
    }
    float4 g4 = ((const float4*)gam)[c4];
    float4 b4 = ((const float4*)bet)[c4];
    float4 m4 = ((const float4*)mea)[c4];
    float4 v4 = ((const float4*)var)[c4];
    ushort4 r4;
    r4.x = f2b((sx * 0.25f - m4.x) * rsqrtf(v4.x + 1e-5f) * g4.x + b4.x);
    r4.y = f2b((sy * 0.25f - m4.y) * rsqrtf(v4.y + 1e-5f) * g4.y + b4.y);
    r4.z = f2b((sz * 0.25f - m4.z) * rsqrtf(v4.z + 1e-5f) * g4.z + b4.z);
    r4.w = f2b((sw * 0.25f - m4.w) * rsqrtf(v4.w + 1e-5f) * g4.w + b4.w);
    ((ushort4*)xpb)[i] = r4;
  } else if (bid < 1320) {
    int i = (bid - 1176) * 256 + threadIdx.x;   // < 36864 = 147456/4
    float4 va = ((const float4*)Wq)[i];
    float4 vb = ((const float4*)Wk)[i];
    float4 vc = ((const float4*)Wv)[i];
    float4 vd = ((const float4*)Wp)[i];
    ushort4 ra; ra.x = f2b(va.x); ra.y = f2b(va.y); ra.z = f2b(va.z); ra.w = f2b(va.w);
    ushort4 rb; rb.x = f2b(vb.x); rb.y = f2b(vb.y); rb.z = f2b(vb.z); rb.w = f2b(vb.w);
    ushort4 rc; rc.x = f2b(vc.x); rc.y = f2b(vc.y); rc.z = f2b(vc.z); rc.w = f2b(vc.w);
    ushort4 rd; rd.x = f2b(vd.x); rd.y = f2b(vd.y); rd.z = f2b(vd.z); rd.w = f2b(vd.w);
    ((ushort4*)wq)[i] = ra; ((ushort4*)wk)[i] = rb;
    ((ushort4*)wv)[i] = rc; ((ushort4*)wp)[i] = rd;
  } else {
    // zero vt κ-pad [768,832) for all 1536 (b,h,d) rows
    int i = (bid - 1320) * 256 + threadIdx.x;   // < 24576
    int row = i >> 4, quad = i & 15;
    ushort4 z; z.x = 0; z.y = 0; z.z = 0; z.w = 0;
    *(ushort4*)&vt[(size_t)row * KPAD + 768 + quad * 4] = z;
  }
}

// ---------------- GEMM body: C[64 x 128] = A[64xK] * W[128 cols][K]^T + bias --
// LDS layout [kchunk][row] 16B units -> conflict-free ds_read_b128.
// 2-phase pipeline: stage kk+1, compute kk, vmcnt(0)+s_barrier once per step.
// epi: 0 bf16 row-major (scaled by oscale), 1 bf16 κ'-scatter vt, 2 fp32.
__device__ __forceinline__ void gemm_body(
    const unsigned short* __restrict__ A, const unsigned short* __restrict__ Bt,
    const float* __restrict__ bias, void* __restrict__ out,
    int row0, int col0, int epi, float oscale,
    unsigned short (*sA)[2048], unsigned short (*sB)[4096]) {
  const int t = threadIdx.x, w = t >> 6, l = t & 63;
  const int wr = w >> 1, wc = w & 1;

  f32x4 acc[2][4];
#pragma unroll
  for (int m = 0; m < 2; ++m)
#pragma unroll
    for (int n = 0; n < 4; ++n) acc[m][n] = (f32x4){0.f, 0.f, 0.f, 0.f};

  auto STAGE = [&](int kk, int bsel) {
    gload16(A + (size_t)(row0 + l) * CCH + kk * 32 + w * 8,
            (char*)sA[bsel] + w * 1024);
    gload16(Bt + (size_t)(col0 + l) * CCH + kk * 32 + w * 8,
            (char*)sB[bsel] + w * 2048);
    gload16(Bt + (size_t)(col0 + 64 + l) * CCH + kk * 32 + w * 8,
            (char*)sB[bsel] + w * 2048 + 1024);
  };

  STAGE(0, 0);
  asm volatile("s_waitcnt vmcnt(0)" ::: "memory");
  __builtin_amdgcn_s_barrier();

  for (int kk = 0; kk < 12; ++kk) {
    const int cur = kk & 1;
    if (kk < 11) STAGE(kk + 1, cur ^ 1);
    bf16x8 af[2], bfv[4];
#pragma unroll
    for (int m = 0; m < 2; ++m)
      af[m] = ldsb8(&sA[cur][(l >> 4) * 512 + (wr * 32 + m * 16 + (l & 15)) * 8]);
#pragma unroll
    for (int n = 0; n < 4; ++n)
      bfv[n] = ldsb8(&sB[cur][(l >> 4) * 1024 + (wc * 64 + n * 16 + (l & 15)) * 8]);
#pragma unroll
    for (int m = 0; m < 2; ++m)
#pragma unroll
      for (int n = 0; n < 4; ++n)
        acc[m][n] = __builtin_amdgcn_mfma_f32_16x16x32_bf16(af[m], bfv[n], acc[m][n], 0, 0, 0);
    if (kk < 11) {
      asm volatile("s_waitcnt vmcnt(0)" ::: "memory");
      __builtin_amdgcn_s_barrier();
    }
  }

#pragma unroll
  for (int m = 0; m < 2; ++m) {
#pragma unroll
    for (int r = 0; r < 4; ++r) {
      int row = row0 + wr * 32 + m * 16 + (l >> 4) * 4 + r;
#pragma unroll
      for (int n = 0; n < 4; ++n) {
        int col = col0 + wc * 64 + n * 16 + (l & 15);
        float v = (acc[m][n][r] + bias[col]) * oscale;
        if (epi == 0) {
          ((unsigned short*)out)[(size_t)row * CCH + col] =
              __builtin_bit_cast(unsigned short, (__bf16)v);
        } else if (epi == 2) {
          ((float*)out)[(size_t)row * CCH + col] = v;
        } else {
          int b_ = row / NKV, j = row - b_ * NKV;
          int h_ = col >> 5, d = col & 31;
          int loc = j & 63;
          // κ' = (n&1)*32 + hi*8 + (n>>1)*4 + r for loc = n*16 + hi*4 + r
          int kap = (j & ~63) + ((loc & 16) << 1) + ((loc & 12) << 1) +
                    ((loc & 32) >> 3) + (loc & 3);
          ((unsigned short*)out)[((size_t)((b_ * 12 + h_) * 32 + d)) * KPAD + kap] =
              __builtin_bit_cast(unsigned short, (__bf16)v);
        }
      }
    }
  }
}

// fused q/k/v projection: grid.x = 196(q) + 49(k) + 49(v), grid.y = 3 col-blocks
__global__ __launch_bounds__(256) void qkv_kernel(
    const unsigned short* __restrict__ xb, const unsigned short* __restrict__ xpb,
    const unsigned short* __restrict__ wq, const unsigned short* __restrict__ wk,
    const unsigned short* __restrict__ wv,
    const float* __restrict__ bq, const float* __restrict__ bk,
    const float* __restrict__ bv,
    unsigned short* __restrict__ q_b, unsigned short* __restrict__ k_b,
    unsigned short* __restrict__ vt_b) {
  __shared__ unsigned short sA[2][2048];
  __shared__ unsigned short sB[2][4096];
  int bx = blockIdx.x;
  const unsigned short *Ap, *Wp_;
  const float* bp_;
  void* op;
  int epi, row0;
  float osc;
  if (bx < 196)      { Ap = xb;  Wp_ = wq; bp_ = bq; op = q_b;  epi = 0; row0 = bx * 64;         osc = SC2; }
  else if (bx < 245) { Ap = xpb; Wp_ = wk; bp_ = bk; op = k_b;  epi = 0; row0 = (bx - 196) * 64; osc = 1.f; }
  else               { Ap = xpb; Wp_ = wv; bp_ = bv; op = vt_b; epi = 1; row0 = (bx - 245) * 64; osc = 1.f; }
  gemm_body(Ap, Wp_, bp_, op, row0, blockIdx.y * 128, epi, osc, sA, sB);
}

__global__ __launch_bounds__(256) void outproj_kernel(
    const unsigned short* __restrict__ ob, const unsigned short* __restrict__ wp,
    const float* __restrict__ bp_, float* __restrict__ out) {
  __shared__ unsigned short sA[2][2048];
  __shared__ unsigned short sB[2][4096];
  gemm_body(ob, wp, bp_, (void*)out, blockIdx.x * 64, blockIdx.y * 128, 2, 1.f, sA, sB);
}

// ---------------- flash attention (no-max softmax, register-resident P) -----
// grid: b*H*(N/64). 4 waves, wave w owns q rows [q0+16w, q0+16w+16).
// Swapped QK^T: s[n] = mfma(K,Q) -> lane holds P[q=c][kv=n*16+hi*4+r].
// κ'-permuted V makes lane-local packed P the PV A-fragment directly.
__global__ __launch_bounds__(256) void attn_kernel(
    const unsigned short* __restrict__ qb, const unsigned short* __restrict__ kb,
    const unsigned short* __restrict__ vtb, unsigned short* __restrict__ ob) {
  __shared__ unsigned short sQ[2048];       // [4 kchunk][64 qrow] x8
  __shared__ unsigned short sK[2][2048];    // [4 kchunk][64 j] x8
  __shared__ unsigned short sV[2][2048];    // [8 κ'chunk][32 d] x8

  const int bx = blockIdx.x;
  const int qt = bx % 49;
  const int h = (bx / 49) % 12;
  const int b = bx / 588;
  const int t = threadIdx.x, w = t >> 6, l = t & 63;
  const int q0 = qt * 64;
  const int hi = l >> 4, c = l & 15;

  auto stageKV = [&](int ttile, int bsel) {
    int j = ttile * 64 + l; if (j > NKV - 1) j = NKV - 1;
    gload16(kb + ((size_t)(b * NKV + j)) * CCH + h * 32 + w * 8,
            (char*)sK[bsel] + w * 1024);
    int kap = ttile * 64 + (2 * w + (l >> 5)) * 8;   // κ' index, KPAD row = no OOB
    gload16(vtb + ((size_t)((b * 12 + h) * 32 + (l & 31))) * KPAD + kap,
            (char*)sV[bsel] + w * 1024);
  };

  // prologue: Q + tile 0
  gload16(qb + ((size_t)(b * NTOK + q0 + l)) * CCH + h * 32 + w * 8,
          (char*)sQ + w * 1024);
  stageKV(0, 0);
  asm volatile("s_waitcnt vmcnt(0)" ::: "memory");
  __builtin_amdgcn_s_barrier();

  const bf16x8 aq = ldsb8(&sQ[hi * 512 + (w * 16 + c) * 8]);   // B-frag: Q row c
  bf16x8 ones;
#pragma unroll
  for (int i = 0; i < 8; ++i) ones[i] = (__bf16)1.0f;

  f32x4 acc0 = (f32x4){0.f, 0.f, 0.f, 0.f};
  f32x4 acc1 = (f32x4){0.f, 0.f, 0.f, 0.f};
  f32x4 accl = (f32x4){0.f, 0.f, 0.f, 0.f};

  for (int tt = 0; tt < 13; ++tt) {
    const int cur = tt & 1;
    if (tt < 12) stageKV(tt + 1, cur ^ 1);

    // swapped QK^T: A = K rows (window n*16..+15), B = Q (this wave's 16 rows)
    // lane gets s[n][r] = S[q = w*16+c][kv = n*16 + hi*4 + r]  (Q pre-scaled)
    f32x4 s[4];
#pragma unroll
    for (int n = 0; n < 4; ++n) {
      bf16x8 kf = ldsb8(&sK[cur][hi * 512 + (n * 16 + c) * 8]);
      s[n] = __builtin_amdgcn_mfma_f32_16x16x32_bf16(kf, aq, (f32x4){0.f, 0.f, 0.f, 0.f}, 0, 0, 0);
    }

    float p[4][4];
#pragma unroll
    for (int n = 0; n < 4; ++n)
#pragma unroll
      for (int r = 0; r < 4; ++r) {
        float e;
        asm("v_exp_f32 %0, %1" : "=v"(e) : "v"(s[n][r]));
        p[n][r] = e;
      }
    if (tt == 12) {   // kv = 768 + n*16 + hi*4 + r valid only for n==0
#pragma unroll
      for (int n = 1; n < 4; ++n)
#pragma unroll
        for (int r = 0; r < 4; ++r) p[n][r] = 0.f;
    }

    // lane-local A-frags: κ' = (n&1)*32 + hi*8 + (n>>1)*4 + r
    // pa[kkk] element e (= e1*4 + rr) is p[2*e1 + kkk][rr]
    bf16x8 pa0, pa1;
#pragma unroll
    for (int rr = 0; rr < 4; ++rr) {
      pa0[rr] = (__bf16)p[0][rr];
      pa0[4 + rr] = (__bf16)p[2][rr];
      pa1[rr] = (__bf16)p[1][rr];
      pa1[4 + rr] = (__bf16)p[3][rr];
    }

    // PV + rowsum: B-frag V[κ' = kkk*32 + hi*8 + e][d]
#pragma unroll
    for (int kkk = 0; kkk < 2; ++kkk) {
      bf16x8 pa = kkk ? pa1 : pa0;
      bf16x8 v0 = ldsb8(&sV[cur][(kkk * 4 + hi) * 256 + c * 8]);
      bf16x8 v1 = ldsb8(&sV[cur][(kkk * 4 + hi) * 256 + (16 + c) * 8]);
      acc0 = __builtin_amdgcn_mfma_f32_16x16x32_bf16(pa, v0, acc0, 0, 0, 0);
      acc1 = __builtin_amdgcn_mfma_f32_16x16x32_bf16(pa, v1, acc1, 0, 0, 0);
      accl = __builtin_amdgcn_mfma_f32_16x16x32_bf16(pa, ones, accl, 0, 0, 0);
    }

    if (tt < 12) {
      asm volatile("s_waitcnt vmcnt(0)" ::: "memory");
      __builtin_amdgcn_s_barrier();
    }
  }

#pragma unroll
  for (int r = 0; r < 4; ++r) {
    int row = q0 + w * 16 + hi * 4 + r;
    float inv = 1.f / accl[r];
    size_t base = ((size_t)(b * NTOK + row)) * CCH + h * 32;
    ob[base + c] = __builtin_bit_cast(unsigned short, (__bf16)(acc0[r] * inv));
    ob[base + 16 + c] = __builtin_bit_cast(unsigned short, (__bf16)(acc1[r] * inv));
  }
}

// ---------------- launch ----------------

extern "C" void kernel_launch(void* const* d_in, const int* in_sizes, int n_in,
                              void* d_out, int out_size, void* d_ws, size_t ws_size,
                              hipStream_t stream) {
  const float* x   = (const float*)d_in[0];
  const float* Wq  = (const float*)d_in[1];
  const float* bq  = (const float*)d_in[2];
  const float* Wk  = (const float*)d_in[3];
  const float* bk  = (const float*)d_in[4];
  const float* Wv  = (const float*)d_in[5];
  const float* bv  = (const float*)d_in[6];
  const float* Wp  = (const float*)d_in[7];
  const float* bp  = (const float*)d_in[8];
  const float* gam = (const float*)d_in[9];
  const float* bet = (const float*)d_in[10];
  const float* mea = (const float*)d_in[11];
  const float* var = (const float*)d_in[12];

  unsigned short* wq_b = (unsigned short*)d_ws;
  unsigned short* wk_b = wq_b + 147456;
  unsigned short* wv_b = wk_b + 147456;
  unsigned short* wp_b = wv_b + 147456;
  unsigned short* xb   = wp_b + 147456;          // [12544][384]
  unsigned short* x_b  = xb + 12544 * 384;       // [3136][384]
  unsigned short* q_b  = x_b + 3136 * 384;       // [12544][384] (pre-scaled)
  unsigned short* k_b  = q_b + 12544 * 384;      // [3136][384]
  unsigned short* vt_b = k_b + 3136 * 384;       // [4][12][32][832] κ'-permuted
  unsigned short* o_b  = vt_b + 1536 * KPAD;     // [12544][384]

  prep_kernel<<<1416, 256, 0, stream>>>(x, gam, bet, mea, var, Wq, Wk, Wv, Wp,
                                        xb, x_b, wq_b, wk_b, wv_b, wp_b, vt_b);
  qkv_kernel<<<dim3(294, 3), 256, 0, stream>>>(xb, x_b, wq_b, wk_b, wv_b,
                                               bq, bk, bv, q_b, k_b, vt_b);
  attn_kernel<<<2352, 256, 0, stream>>>(q_b, k_b, vt_b, o_b);
  outproj_kernel<<<dim3(196, 3), 256, 0, stream>>>(o_b, wp_b, bp, (float*)d_out);
}